// Round 3
// baseline (164.277 us; speedup 1.0000x reference)
//
#include <hip/hip_runtime.h>
#include <stdint.h>

#define HEADS 4
#define DHEAD 32
#define NTOK  4096
#define CDIM  256
#define HID   128
#define NBATCH 4

typedef __bf16 bf16x8 __attribute__((ext_vector_type(8)));
typedef __bf16 bf16x4 __attribute__((ext_vector_type(4)));
typedef __bf16 bf16x2 __attribute__((ext_vector_type(2)));
typedef float  f32x4  __attribute__((ext_vector_type(4)));
typedef unsigned int u32x4 __attribute__((ext_vector_type(4)));

// softmax scale folded with log2(e) into Q so scores are in base-2 domain
#define QSCALE (0.17677669529663689f * 1.4426950408889634f)

#define MFMA __builtin_amdgcn_mfma_f32_16x16x32_bf16

// async global->LDS DMA, 16B per lane; LDS dest = uniform base + lane*16
#define ASYNC16(gp, lp)                                                        \
    __builtin_amdgcn_global_load_lds(                                          \
        (const __attribute__((address_space(1))) unsigned int*)(gp),           \
        (__attribute__((address_space(3))) unsigned int*)(lp), 16, 0, 0)

// pack two f32 -> one u32 of 2 bf16 (compiler emits v_cvt_pk_bf16_f32)
__device__ __forceinline__ unsigned pack_bf16(float lo, float hi)
{
    bf16x2 c = { (__bf16)lo, (__bf16)hi };
    return __builtin_bit_cast(unsigned, c);
}

// 4x4 word transpose across 16-lane groups: (a,b) -> rows via
// permlane32_swap then permlane16_swap (gfx950 builtins, {vdst,vsrc} pair)
__device__ __forceinline__ void xpose_swap(unsigned& a, unsigned& b)
{
    auto s = __builtin_amdgcn_permlane32_swap(a, b, false, false);
    auto t = __builtin_amdgcn_permlane16_swap(s[0], s[1], false, false);
    a = t[0];
    b = t[1];
}

// ---------------------------------------------------------------------------
// cast_x: x[b][c][p] f32 -> Xt[b][p][c] bf16.  Vectorized: float4 global
// reads, bf16x8 (16B) global stores; LDS transpose with 2-way (free) banking.
// ---------------------------------------------------------------------------
__global__ __launch_bounds__(256) void cast_x(const float* __restrict__ x,
                                              __bf16* __restrict__ Xt)
{
    __shared__ float xs[64][65];
    const int t = threadIdx.x;
    const int p0 = blockIdx.x * 64;      // 64 tiles
    const int c0 = blockIdx.y * 64;      // 4 tiles
    const int b  = blockIdx.z;           // 4

    const int p4 = (t & 15) * 4;
#pragma unroll
    for (int k = 0; k < 4; ++k) {        // float4 coalesced reads
        const int c = (t >> 4) + k * 16;
        f32x4 v = *(const f32x4*)(x + ((size_t)(b * CDIM + c0 + c)) * NTOK + p0 + p4);
#pragma unroll
        for (int i = 0; i < 4; ++i) xs[c][p4 + i] = v[i];   // 2-way banks: free
    }
    __syncthreads();

    const int c8 = t & 7;
#pragma unroll
    for (int m = 0; m < 2; ++m) {
        const int p = (t >> 3) + m * 32;
        bf16x8 o;
#pragma unroll
        for (int u = 0; u < 8; ++u) o[u] = (__bf16)xs[c8 * 8 + u][p];  // 2-way: free
        *(bf16x8*)(Xt + ((size_t)(b * NTOK + p0 + p)) * CDIM + c0 + c8 * 8) = o;
    }
}

// ---------------------------------------------------------------------------
// qkv_gemm: DMA-staged.  Block = 128 p x 64 o (4 waves x 16 o), K=256.
// A-frags built from fp32 weights (in-register cvt) -> no cast_w kernel.
// ---------------------------------------------------------------------------
__global__ __launch_bounds__(256) void qkv_gemm(
    const float* __restrict__ wq, const __bf16* __restrict__ Xt,
    __bf16* __restrict__ Q, __bf16* __restrict__ K, __bf16* __restrict__ Vt)
{
    __shared__ __bf16 Xs[128 * 256];     // 64 KB, swizzled

    const int t  = threadIdx.x;
    const int pt = blockIdx.x;           // 32 (128 p each)
    const int ot = blockIdx.y;           // 6  (64 o each)
    const int b  = blockIdx.z;           // 4
    const int l = t & 63, lm = l & 15, q4 = l >> 4;
    const int w = __builtin_amdgcn_readfirstlane(t >> 6);
    const int p0 = pt * 128;
    const int o0w = ot * 64 + w * 16;

    // DMA the Xt tile (swizzled gather): 16 instrs/wave, 1 KB each
#pragma unroll
    for (int i = 0; i < 16; ++i) {
        const int p_l = (i * 4 + w) * 2 + (l >> 5);
        const int gc  = (l & 31) ^ (p_l & 7);
        const __bf16* gp = Xt + ((size_t)(b * NTOK + p0 + p_l)) * CDIM + gc * 8;
        ASYNC16(gp, (char*)Xs + (i * 4 + w) * 1024);
    }

    // A fragments from fp32 weights (independent loads overlap the DMA)
    bf16x8 af[8];
#pragma unroll
    for (int kt = 0; kt < 8; ++kt) {
        const float* wr = wq + (size_t)(o0w + lm) * CDIM + kt * 32 + q4 * 8;
        f32x4 w0 = *(const f32x4*)wr;
        f32x4 w1 = *(const f32x4*)(wr + 4);
#pragma unroll
        for (int u = 0; u < 4; ++u) {
            af[kt][u]     = (__bf16)w0[u];
            af[kt][u + 4] = (__bf16)w1[u];
        }
    }
    __syncthreads();

    f32x4 acc[8] = {};
#pragma unroll
    for (int kt = 0; kt < 8; ++kt) {
#pragma unroll
        for (int nf = 0; nf < 8; ++nf) {
            const int p = nf * 16 + lm;
            bf16x8 bf = *(const bf16x8*)(
                (const char*)Xs + p * 512 + (((kt * 4 + q4) ^ (lm & 7)) * 16));
            acc[nf] = MFMA(af[kt], bf, acc[nf], 0, 0, 0);
        }
    }

    const int og0  = o0w + q4 * 4;       // r=0..3 stay in one head
    const int which = og0 >> 7;          // uniform per (ot,w)
    const int head  = (og0 >> 5) & 3;
    const int d0    = og0 & 31;
    const int bh    = b * HEADS + head;
#pragma unroll
    for (int nf = 0; nf < 8; ++nf) {
        const int p_g = p0 + nf * 16 + lm;
        f32x4 a = acc[nf];
        if (which == 0) {
            bf16x4 pk = { (__bf16)(a[0] * QSCALE), (__bf16)(a[1] * QSCALE),
                          (__bf16)(a[2] * QSCALE), (__bf16)(a[3] * QSCALE) };
            *(bf16x4*)(Q + ((size_t)bh * NTOK + p_g) * DHEAD + d0) = pk;
        } else if (which == 1) {
            bf16x4 pk = { (__bf16)a[0], (__bf16)a[1], (__bf16)a[2], (__bf16)a[3] };
            *(bf16x4*)(K + ((size_t)bh * NTOK + p_g) * DHEAD + d0) = pk;
        } else {
#pragma unroll
            for (int r = 0; r < 4; ++r)
                Vt[((size_t)(bh * DHEAD + d0 + r)) * NTOK + p_g] = (__bf16)a[r];
        }
    }
}

// ---------------------------------------------------------------------------
// attn: LDS-staged (K/V only), double-buffered flash attention, split-j x4,
// g=4 row groups per wave (256 Q rows/block).
// P never touches LDS.  QK^T output (lane(lm,q4) holds P[16j4+4q4+r][lm])
// is packed to bf16 words and transposed into the PV A-fragment layout
// (P[lm][8q4+u]) with a permlane32_swap -> permlane16_swap butterfly
// (exact 4x4 word transpose across the q4 lane groups).  The 4 g-chains are
// fully independent and register-resident.  Row sums via f32 add tree
// (ones-MFMA removed: -20% MFMA pipe work); cross-q4 reduce at epilogue.
// ---------------------------------------------------------------------------
__global__ __launch_bounds__(256, 4) void attn(
    const __bf16* __restrict__ Q, const __bf16* __restrict__ K,
    const __bf16* __restrict__ Vt, __bf16* __restrict__ Opart,
    float* __restrict__ Lsum)
{
    __shared__ uint4  KbufU[2][256];               // [buf][64 rows x 64 B]
    __shared__ uint4  VbufU[2][256];               // [buf][32 rows x 128 B]

    const int t   = threadIdx.x;
    const int blk = blockIdx.x;                    // 1024
    const int bh  = blk & 15;
    const int rest = blk >> 4;                     // 0..63
    const int qt   = rest & 15;                    // 16 tiles of 256 rows
    const int sp   = rest >> 4;                    // j-split 0..3
    const int l = t & 63, lm = l & 15, q4 = l >> 4;
    const int wu = __builtin_amdgcn_readfirstlane(t >> 6);
    const int row0 = qt * 256 + wu * 64;

    const int jt0 = sp * 16, jt1 = jt0 + 16;

    bf16x8 qf[4];
#pragma unroll
    for (int g = 0; g < 4; ++g)
        qf[g] = *(const bf16x8*)(Q + ((size_t)bh * NTOK + row0 + g * 16 + lm) * DHEAD + q4 * 8);

    const char* KbT = (const char*)(K  + (size_t)bh * NTOK * DHEAD);
    const char* VbT = (const char*)(Vt + (size_t)bh * DHEAD * NTOK);

    const int sK_r  = wu * 16 + (l >> 2);
    const int sK_gc = (l & 3) ^ ((sK_r >> 1) & 3);
    const int sV_r  = wu * 8 + (l >> 3);
    const int sV_gc = (l & 7) ^ (sV_r & 7);

    f32x4 o[4][2] = {};
    float Lp[4] = { 0.f, 0.f, 0.f, 0.f };

    {
        const int j00 = jt0 * 64;
        const char* gk = KbT + (size_t)(j00 + sK_r) * 64 + sK_gc * 16;
        ASYNC16(gk, (char*)&KbufU[0][0] + wu * 1024);
        const char* gv = VbT + (size_t)sV_r * (NTOK * 2) + (size_t)j00 * 2 + sV_gc * 16;
        ASYNC16(gv, (char*)&VbufU[0][0] + wu * 1024);
    }
    __syncthreads();

    for (int jt = jt0; jt < jt1; ++jt) {
        const int buf = (jt - jt0) & 1;
        if (jt + 1 < jt1) {
            const int j0n = (jt + 1) * 64;
            const char* gk = KbT + (size_t)(j0n + sK_r) * 64 + sK_gc * 16;
            ASYNC16(gk, (char*)&KbufU[buf ^ 1][0] + wu * 1024);
            const char* gv = VbT + (size_t)sV_r * (NTOK * 2) + (size_t)j0n * 2 + sV_gc * 16;
            ASYNC16(gv, (char*)&VbufU[buf ^ 1][0] + wu * 1024);
        }

        const __bf16* Kl = (const __bf16*)&KbufU[buf][0];
        const __bf16* Vl = (const __bf16*)&VbufU[buf][0];

        bf16x8 kf[4];
#pragma unroll
        for (int j4 = 0; j4 < 4; ++j4) {
            int jl = j4 * 16 + lm;
            int cs = q4 ^ ((jl >> 1) & 3);
            kf[j4] = *(const bf16x8*)(Kl + jl * 32 + cs * 8);
        }
        const int swv = lm & 7;
        bf16x8 vf[4];
        vf[0] = *(const bf16x8*)(Vl + lm * 64        + ((q4    ) ^ swv) * 8);
        vf[1] = *(const bf16x8*)(Vl + (16 + lm) * 64 + ((q4    ) ^ swv) * 8);
        vf[2] = *(const bf16x8*)(Vl + lm * 64        + ((4 + q4) ^ swv) * 8);
        vf[3] = *(const bf16x8*)(Vl + (16 + lm) * 64 + ((4 + q4) ^ swv) * 8);

#pragma unroll
        for (int g = 0; g < 4; ++g) {
            f32x4 st[4];
            __builtin_amdgcn_s_setprio(1);
#pragma unroll
            for (int j4 = 0; j4 < 4; ++j4) {
                f32x4 z = {};
                st[j4] = MFMA(kf[j4], qf[g], z, 0, 0, 0);
            }
            __builtin_amdgcn_s_setprio(0);

            // exp2 + packed-bf16 cvt + row-sum partial, per j4 quad
            unsigned pw[8];
            float lq = 0.f;
#pragma unroll
            for (int j4 = 0; j4 < 4; ++j4) {
                float p0 = __builtin_amdgcn_exp2f(st[j4][0]);
                float p1 = __builtin_amdgcn_exp2f(st[j4][1]);
                float p2 = __builtin_amdgcn_exp2f(st[j4][2]);
                float p3 = __builtin_amdgcn_exp2f(st[j4][3]);
                lq += (p0 + p1) + (p2 + p3);
                pw[2 * j4]     = pack_bf16(p0, p1);
                pw[2 * j4 + 1] = pack_bf16(p2, p3);
            }
            Lp[g] += lq;

            // 4x4 word transpose across q4 lane groups:
            //   (A,B) = swap32(w[j4lo][c], w[j4hi][c]);
            //   (k=c, k=2+c) = swap16(A, B)
            unsigned a0 = pw[0], b0 = pw[2];
            xpose_swap(a0, b0);
            unsigned a1 = pw[1], b1 = pw[3];
            xpose_swap(a1, b1);
            u32x4 pq0 = { a0, a1, b0, b1 };
            bf16x8 pf0 = __builtin_bit_cast(bf16x8, pq0);

            unsigned a2 = pw[4], b2 = pw[6];
            xpose_swap(a2, b2);
            unsigned a3 = pw[5], b3 = pw[7];
            xpose_swap(a3, b3);
            u32x4 pq1 = { a2, a3, b2, b3 };
            bf16x8 pf1 = __builtin_bit_cast(bf16x8, pq1);

            __builtin_amdgcn_s_setprio(1);
            o[g][0] = MFMA(pf0, vf[0], o[g][0], 0, 0, 0);
            o[g][1] = MFMA(pf0, vf[1], o[g][1], 0, 0, 0);
            o[g][0] = MFMA(pf1, vf[2], o[g][0], 0, 0, 0);
            o[g][1] = MFMA(pf1, vf[3], o[g][1], 0, 0, 0);
            __builtin_amdgcn_s_setprio(0);
        }
        __syncthreads();
    }

    // cross-q4 reduce of row-sum partials (once per kernel)
#pragma unroll
    for (int g = 0; g < 4; ++g) {
        Lp[g] += __shfl_xor(Lp[g], 16, 64);
        Lp[g] += __shfl_xor(Lp[g], 32, 64);
    }
    {   // lane group q4 stores rows of g==q4: static-index select
        float v0 = (q4 & 1) ? Lp[1] : Lp[0];
        float v1 = (q4 & 1) ? Lp[3] : Lp[2];
        float lv = (q4 & 2) ? v1 : v0;
        Lsum[((size_t)sp * 16 + bh) * NTOK + row0 + q4 * 16 + lm] = lv;
    }

    const int b = bh >> 2, h = bh & 3;
    __bf16* Op = Opart + (size_t)sp * NBATCH * NTOK * HID;
#pragma unroll
    for (int g = 0; g < 4; ++g) {
        const int rowg0 = row0 + g * 16;
#pragma unroll
        for (int r = 0; r < 4; ++r) {
            size_t rowg = (size_t)b * NTOK + rowg0 + q4 * 4 + r;
            Op[rowg * HID + h * DHEAD + lm]      = (__bf16)o[g][0][r];
            Op[rowg * HID + h * DHEAD + 16 + lm] = (__bf16)o[g][1][r];
        }
    }
}

// ---------------------------------------------------------------------------
// combine: Obf[b,p,c] = bf16( sum_sp P_sp[b,p,c] / sum_sp L_sp[b,head(c),p] )
// ---------------------------------------------------------------------------
__global__ __launch_bounds__(256) void combine(
    const __bf16* __restrict__ Opart, const float* __restrict__ Lsum,
    __bf16* __restrict__ Obf)
{
    const int e  = blockIdx.x * 256 + threadIdx.x;   // 1024 blocks
    const int c8 = e & 15;
    const int row = e >> 4;                          // b*NTOK + p
    const int p  = row & (NTOK - 1);
    const int b  = row >> 12;
    const int head = c8 >> 2;

    const size_t li = ((size_t)(b * HEADS + head)) * NTOK + p;
    const float inv = 1.f / (Lsum[li] + Lsum[li + 16 * NTOK] +
                             Lsum[li + 32 * NTOK] + Lsum[li + 48 * NTOK]);

    const size_t per = (size_t)NBATCH * NTOK * HID;
    const size_t base = (size_t)row * HID + c8 * 8;
    bf16x8 x0 = *(const bf16x8*)(Opart + base);
    bf16x8 x1 = *(const bf16x8*)(Opart + per + base);
    bf16x8 x2 = *(const bf16x8*)(Opart + 2 * per + base);
    bf16x8 x3 = *(const bf16x8*)(Opart + 3 * per + base);
    bf16x8 o;
#pragma unroll
    for (int u = 0; u < 8; ++u)
        o[u] = (__bf16)((((float)x0[u] + (float)x1[u]) +
                         ((float)x2[u] + (float)x3[u])) * inv);
    *(bf16x8*)(Obf + base) = o;
}

// ---------------------------------------------------------------------------
// out_gemm: DMA-staged.  Block = 128 p x 64 o, K=128; fp32 weights in-reg cvt.
// out[b,o,p] = bias[o] + sum_c Wo[o,c] * Obf[b,p,c]
// ---------------------------------------------------------------------------
__global__ __launch_bounds__(256) void out_gemm(
    const float* __restrict__ wo, const __bf16* __restrict__ Obf,
    const float* __restrict__ bias, float* __restrict__ out)
{
    __shared__ __bf16 Bs[128 * 128];     // 32 KB, swizzled

    const int t  = threadIdx.x;
    const int pt = blockIdx.x;           // 32
    const int ot = blockIdx.y;           // 4 (64 o each)
    const int b  = blockIdx.z;           // 4
    const int l = t & 63, lm = l & 15, q4 = l >> 4;
    const int w = __builtin_amdgcn_readfirstlane(t >> 6);
    const int p0 = pt * 128;
    const int o0w = ot * 64 + w * 16;

#pragma unroll
    for (int i = 0; i < 8; ++i) {        // 32 KB: 8 instrs/wave
        const int p_l = (i * 4 + w) * 4 + (l >> 4);
        const int gc  = (l & 15) ^ (p_l & 7);
        const __bf16* gp = Obf + ((size_t)(b * NTOK + p0 + p_l)) * HID + gc * 8;
        ASYNC16(gp, (char*)Bs + (i * 4 + w) * 1024);
    }

    bf16x8 af[4];
#pragma unroll
    for (int kt = 0; kt < 4; ++kt) {
        const float* wr = wo + (size_t)(o0w + lm) * HID + kt * 32 + q4 * 8;
        f32x4 w0 = *(const f32x4*)wr;
        f32x4 w1 = *(const f32x4*)(wr + 4);
#pragma unroll
        for (int u = 0; u < 4; ++u) {
            af[kt][u]     = (__bf16)w0[u];
            af[kt][u + 4] = (__bf16)w1[u];
        }
    }
    __syncthreads();

    f32x4 acc[8] = {};
#pragma unroll
    for (int kt = 0; kt < 4; ++kt) {
#pragma unroll
        for (int nf = 0; nf < 8; ++nf) {
            const int p = nf * 16 + lm;
            bf16x8 bf = *(const bf16x8*)(
                (const char*)Bs + p * 256 + (((kt * 4 + q4) ^ (lm & 7)) * 16));
            acc[nf] = MFMA(af[kt], bf, acc[nf], 0, 0, 0);
        }
    }

    const int og0 = o0w + q4 * 4;
#pragma unroll
    for (int nf = 0; nf < 8; ++nf) {
        const int p_g = p0 + nf * 16 + lm;
#pragma unroll
        for (int r = 0; r < 4; ++r)
            out[((size_t)(b * CDIM + og0 + r)) * NTOK + p_g] =
                acc[nf][r] + bias[og0 + r];
    }
}

// ---------------------------------------------------------------------------
extern "C" void kernel_launch(void* const* d_in, const int* in_sizes, int n_in,
                              void* d_out, int out_size, void* d_ws, size_t ws_size,
                              hipStream_t stream)
{
    const float* x     = (const float*)d_in[0];
    const float* w_qkv = (const float*)d_in[1];
    const float* w_out = (const float*)d_in[2];
    const float* b_out = (const float*)d_in[3];
    float* out = (float*)d_out;

    __bf16* Xt = (__bf16*)d_ws;                           // 8 MB
    __bf16* Q  = Xt + (size_t)NBATCH * NTOK * CDIM;       // 4 MB each
    __bf16* K  = Q  + (size_t)16 * NTOK * DHEAD;
    __bf16* Vt = K  + (size_t)16 * NTOK * DHEAD;
    __bf16* Opart = Vt + (size_t)16 * NTOK * DHEAD;       // 4 x 4 MB (bf16)
    __bf16* Obf   = Opart + (size_t)4 * NBATCH * NTOK * HID;   // 4 MB
    float*  Lsum  = (float*)(Obf + (size_t)NBATCH * NTOK * HID); // 4 x 256 KB

    cast_x  <<<dim3(64, 4, NBATCH), 256, 0, stream>>>(x, Xt);
    qkv_gemm<<<dim3(32, 6, NBATCH), 256, 0, stream>>>(w_qkv, Xt, Q, K, Vt);
    attn    <<<1024, 256, 0, stream>>>(Q, K, Vt, Opart, Lsum);
    combine <<<1024, 256, 0, stream>>>(Opart, Lsum, Obf);
    out_gemm<<<dim3(32, 4, NBATCH), 256, 0, stream>>>(w_out, Obf, b_out, out);
}

// Round 4
// 146.886 us; speedup vs baseline: 1.1184x; 1.1184x over previous
//
#include <hip/hip_runtime.h>
#include <stdint.h>

#define HEADS 4
#define DHEAD 32
#define NTOK  4096
#define CDIM  256
#define HID   128
#define NBATCH 4

typedef __bf16 bf16x8 __attribute__((ext_vector_type(8)));
typedef __bf16 bf16x4 __attribute__((ext_vector_type(4)));
typedef float  f32x4  __attribute__((ext_vector_type(4)));

// softmax scale folded with log2(e) into Q so scores are in base-2 domain
#define QSCALE (0.17677669529663689f * 1.4426950408889634f)

#define MFMA __builtin_amdgcn_mfma_f32_16x16x32_bf16

// async global->LDS DMA, 16B per lane; LDS dest = uniform base + lane*16
#define ASYNC16(gp, lp)                                                        \
    __builtin_amdgcn_global_load_lds(                                          \
        (const __attribute__((address_space(1))) unsigned int*)(gp),           \
        (__attribute__((address_space(3))) unsigned int*)(lp), 16, 0, 0)

// ---------------------------------------------------------------------------
// cast_x: x[b][c][p] f32 -> Xt[b][p][c] bf16.  Vectorized: float4 global
// reads, bf16x8 (16B) global stores; LDS transpose with 2-way (free) banking.
// ---------------------------------------------------------------------------
__global__ __launch_bounds__(256) void cast_x(const float* __restrict__ x,
                                              __bf16* __restrict__ Xt)
{
    __shared__ float xs[64][65];
    const int t = threadIdx.x;
    const int p0 = blockIdx.x * 64;      // 64 tiles
    const int c0 = blockIdx.y * 64;      // 4 tiles
    const int b  = blockIdx.z;           // 4

    const int p4 = (t & 15) * 4;
#pragma unroll
    for (int k = 0; k < 4; ++k) {        // float4 coalesced reads
        const int c = (t >> 4) + k * 16;
        f32x4 v = *(const f32x4*)(x + ((size_t)(b * CDIM + c0 + c)) * NTOK + p0 + p4);
#pragma unroll
        for (int i = 0; i < 4; ++i) xs[c][p4 + i] = v[i];   // 2-way banks: free
    }
    __syncthreads();

    const int c8 = t & 7;
#pragma unroll
    for (int m = 0; m < 2; ++m) {
        const int p = (t >> 3) + m * 32;
        bf16x8 o;
#pragma unroll
        for (int u = 0; u < 8; ++u) o[u] = (__bf16)xs[c8 * 8 + u][p];  // 2-way: free
        *(bf16x8*)(Xt + ((size_t)(b * NTOK + p0 + p)) * CDIM + c0 + c8 * 8) = o;
    }
}

// ---------------------------------------------------------------------------
// qkv_gemm: DMA-staged.  Block = 128 p x 64 o (4 waves x 16 o), K=256.
// A-frags built from fp32 weights (in-register cvt) -> no cast_w kernel.
// ---------------------------------------------------------------------------
__global__ __launch_bounds__(256) void qkv_gemm(
    const float* __restrict__ wq, const __bf16* __restrict__ Xt,
    __bf16* __restrict__ Q, __bf16* __restrict__ K, __bf16* __restrict__ Vt)
{
    __shared__ __bf16 Xs[128 * 256];     // 64 KB, swizzled

    const int t  = threadIdx.x;
    const int pt = blockIdx.x;           // 32 (128 p each)
    const int ot = blockIdx.y;           // 6  (64 o each)
    const int b  = blockIdx.z;           // 4
    const int l = t & 63, lm = l & 15, q4 = l >> 4;
    const int w = __builtin_amdgcn_readfirstlane(t >> 6);
    const int p0 = pt * 128;
    const int o0w = ot * 64 + w * 16;

    // DMA the Xt tile (swizzled gather): 16 instrs/wave, 1 KB each
#pragma unroll
    for (int i = 0; i < 16; ++i) {
        const int p_l = (i * 4 + w) * 2 + (l >> 5);
        const int gc  = (l & 31) ^ (p_l & 7);
        const __bf16* gp = Xt + ((size_t)(b * NTOK + p0 + p_l)) * CDIM + gc * 8;
        ASYNC16(gp, (char*)Xs + (i * 4 + w) * 1024);
    }

    // A fragments from fp32 weights (independent loads overlap the DMA)
    bf16x8 af[8];
#pragma unroll
    for (int kt = 0; kt < 8; ++kt) {
        const float* wr = wq + (size_t)(o0w + lm) * CDIM + kt * 32 + q4 * 8;
        f32x4 w0 = *(const f32x4*)wr;
        f32x4 w1 = *(const f32x4*)(wr + 4);
#pragma unroll
        for (int u = 0; u < 4; ++u) {
            af[kt][u]     = (__bf16)w0[u];
            af[kt][u + 4] = (__bf16)w1[u];
        }
    }
    __syncthreads();

    f32x4 acc[8] = {};
#pragma unroll
    for (int kt = 0; kt < 8; ++kt) {
#pragma unroll
        for (int nf = 0; nf < 8; ++nf) {
            const int p = nf * 16 + lm;
            bf16x8 bf = *(const bf16x8*)(
                (const char*)Xs + p * 512 + (((kt * 4 + q4) ^ (lm & 7)) * 16));
            acc[nf] = MFMA(af[kt], bf, acc[nf], 0, 0, 0);
        }
    }

    const int og0  = o0w + q4 * 4;       // r=0..3 stay in one head
    const int which = og0 >> 7;          // uniform per (ot,w)
    const int head  = (og0 >> 5) & 3;
    const int d0    = og0 & 31;
    const int bh    = b * HEADS + head;
#pragma unroll
    for (int nf = 0; nf < 8; ++nf) {
        const int p_g = p0 + nf * 16 + lm;
        f32x4 a = acc[nf];
        if (which == 0) {
            bf16x4 pk = { (__bf16)(a[0] * QSCALE), (__bf16)(a[1] * QSCALE),
                          (__bf16)(a[2] * QSCALE), (__bf16)(a[3] * QSCALE) };
            *(bf16x4*)(Q + ((size_t)bh * NTOK + p_g) * DHEAD + d0) = pk;
        } else if (which == 1) {
            bf16x4 pk = { (__bf16)a[0], (__bf16)a[1], (__bf16)a[2], (__bf16)a[3] };
            *(bf16x4*)(K + ((size_t)bh * NTOK + p_g) * DHEAD + d0) = pk;
        } else {
#pragma unroll
            for (int r = 0; r < 4; ++r)
                Vt[((size_t)(bh * DHEAD + d0 + r)) * NTOK + p_g] = (__bf16)a[r];
        }
    }
}

// ---------------------------------------------------------------------------
// attn: LDS-staged, double-buffered flash attention, split-j x4, g=4 row
// groups per wave (256 Q rows/block).  r0 structure (LDS Ps + ones-MFMA
// row-sum: keeps row-sum on the idle MFMA pipe, P-traffic on the LDS pipe)
// with two fixes:
//  - Ps is XOR-swizzled ([16][64], byte ^= (lm&7)<<4): the b128 reads become
//    minimum-cycle (r0's padded [16][72] layout was the source of ALL 6.3M
//    bank-conflict cycles -- r3 with Ps removed measured 0).
//  - Ps double-buffered on g-parity: breaks the write-after-read
//    serialization between consecutive g chains.
// ---------------------------------------------------------------------------
__global__ __launch_bounds__(256, 4) void attn(
    const __bf16* __restrict__ Q, const __bf16* __restrict__ K,
    const __bf16* __restrict__ Vt, __bf16* __restrict__ Opart,
    float* __restrict__ Lsum)
{
    __shared__ uint4  KbufU[2][256];               // [buf][64 rows x 64 B]
    __shared__ uint4  VbufU[2][256];               // [buf][32 rows x 128 B]
    __shared__ __bf16 Ps[4][2][16][64];            // per-wave, g-parity dbuf

    const int t   = threadIdx.x;
    const int blk = blockIdx.x;                    // 1024
    const int bh  = blk & 15;
    const int rest = blk >> 4;                     // 0..63
    const int qt   = rest & 15;                    // 16 tiles of 256 rows
    const int sp   = rest >> 4;                    // j-split 0..3
    const int l = t & 63, lm = l & 15, q4 = l >> 4;
    const int wu = __builtin_amdgcn_readfirstlane(t >> 6);
    const int row0 = qt * 256 + wu * 64;

    const int jt0 = sp * 16, jt1 = jt0 + 16;
    const int psw = (lm & 7) << 4;                 // Ps byte swizzle

    bf16x8 qf[4];
#pragma unroll
    for (int g = 0; g < 4; ++g)
        qf[g] = *(const bf16x8*)(Q + ((size_t)bh * NTOK + row0 + g * 16 + lm) * DHEAD + q4 * 8);

    const char* KbT = (const char*)(K  + (size_t)bh * NTOK * DHEAD);
    const char* VbT = (const char*)(Vt + (size_t)bh * DHEAD * NTOK);

    const int sK_r  = wu * 16 + (l >> 2);
    const int sK_gc = (l & 3) ^ ((sK_r >> 1) & 3);
    const int sV_r  = wu * 8 + (l >> 3);
    const int sV_gc = (l & 7) ^ (sV_r & 7);

    bf16x8 ones;
#pragma unroll
    for (int u = 0; u < 8; ++u) ones[u] = (__bf16)1.0f;

    f32x4 o[4][3] = {};

    {
        const int j00 = jt0 * 64;
        const char* gk = KbT + (size_t)(j00 + sK_r) * 64 + sK_gc * 16;
        ASYNC16(gk, (char*)&KbufU[0][0] + wu * 1024);
        const char* gv = VbT + (size_t)sV_r * (NTOK * 2) + (size_t)j00 * 2 + sV_gc * 16;
        ASYNC16(gv, (char*)&VbufU[0][0] + wu * 1024);
    }
    __syncthreads();

    for (int jt = jt0; jt < jt1; ++jt) {
        const int buf = (jt - jt0) & 1;
        if (jt + 1 < jt1) {
            const int j0n = (jt + 1) * 64;
            const char* gk = KbT + (size_t)(j0n + sK_r) * 64 + sK_gc * 16;
            ASYNC16(gk, (char*)&KbufU[buf ^ 1][0] + wu * 1024);
            const char* gv = VbT + (size_t)sV_r * (NTOK * 2) + (size_t)j0n * 2 + sV_gc * 16;
            ASYNC16(gv, (char*)&VbufU[buf ^ 1][0] + wu * 1024);
        }

        const __bf16* Kl = (const __bf16*)&KbufU[buf][0];
        const __bf16* Vl = (const __bf16*)&VbufU[buf][0];

        bf16x8 kf[4];
#pragma unroll
        for (int j4 = 0; j4 < 4; ++j4) {
            int jl = j4 * 16 + lm;
            int cs = q4 ^ ((jl >> 1) & 3);
            kf[j4] = *(const bf16x8*)(Kl + jl * 32 + cs * 8);
        }
        const int swv = lm & 7;
        bf16x8 vf[4];
        vf[0] = *(const bf16x8*)(Vl + lm * 64        + ((q4    ) ^ swv) * 8);
        vf[1] = *(const bf16x8*)(Vl + (16 + lm) * 64 + ((q4    ) ^ swv) * 8);
        vf[2] = *(const bf16x8*)(Vl + lm * 64        + ((4 + q4) ^ swv) * 8);
        vf[3] = *(const bf16x8*)(Vl + (16 + lm) * 64 + ((4 + q4) ^ swv) * 8);

#pragma unroll
        for (int g = 0; g < 4; ++g) {
            char* psb = (char*)&Ps[wu][g & 1][0][0] + lm * 128;

            f32x4 st[4];
            __builtin_amdgcn_s_setprio(1);
#pragma unroll
            for (int j4 = 0; j4 < 4; ++j4) {
                f32x4 z = {};
                st[j4] = MFMA(kf[j4], qf[g], z, 0, 0, 0);
            }
            __builtin_amdgcn_s_setprio(0);
#pragma unroll
            for (int j4 = 0; j4 < 4; ++j4) {
                bf16x4 pk;
                pk[0] = (__bf16)__builtin_amdgcn_exp2f(st[j4][0]);
                pk[1] = (__bf16)__builtin_amdgcn_exp2f(st[j4][1]);
                pk[2] = (__bf16)__builtin_amdgcn_exp2f(st[j4][2]);
                pk[3] = (__bf16)__builtin_amdgcn_exp2f(st[j4][3]);
                *(bf16x4*)(psb + ((j4 * 32 + q4 * 8) ^ psw)) = pk;
            }
            __builtin_amdgcn_s_setprio(1);
#pragma unroll
            for (int jc = 0; jc < 2; ++jc) {
                bf16x8 pf = *(const bf16x8*)(psb + ((jc * 64 + q4 * 16) ^ psw));
                o[g][0] = MFMA(pf, vf[jc * 2 + 0], o[g][0], 0, 0, 0);
                o[g][1] = MFMA(pf, vf[jc * 2 + 1], o[g][1], 0, 0, 0);
                o[g][2] = MFMA(pf, ones,           o[g][2], 0, 0, 0);
            }
            __builtin_amdgcn_s_setprio(0);
        }
        __syncthreads();
    }

    const int b = bh >> 2, h = bh & 3;
    __bf16* Op = Opart + (size_t)sp * NBATCH * NTOK * HID;
#pragma unroll
    for (int g = 0; g < 4; ++g) {
        const int rowg0 = row0 + g * 16;
        if (lm == 0)
            *(f32x4*)(Lsum + ((size_t)sp * 16 + bh) * NTOK + rowg0 + q4 * 4) = o[g][2];
#pragma unroll
        for (int r = 0; r < 4; ++r) {
            size_t rowg = (size_t)b * NTOK + rowg0 + q4 * 4 + r;
            Op[rowg * HID + h * DHEAD + lm]      = (__bf16)o[g][0][r];
            Op[rowg * HID + h * DHEAD + 16 + lm] = (__bf16)o[g][1][r];
        }
    }
}

// ---------------------------------------------------------------------------
// out_gemm (combine fused in): reg-staged.  Each thread loads the 4 Opart
// split slices + Lsum row-sums, combines in-register (identical arithmetic to
// the old combine kernel), and ds_writes the bf16 result into the SAME
// swizzled Bs layout the DMA version produced.  Saves one kernel launch and
// the 8 MB Obf write+read round trip.
// out[b,o,p] = bias[o] + sum_c Wo[o,c] * (sum_sp Opart)/(sum_sp Lsum)
// ---------------------------------------------------------------------------
__global__ __launch_bounds__(256) void out_gemm(
    const float* __restrict__ wo, const __bf16* __restrict__ Opart,
    const float* __restrict__ Lsum, const float* __restrict__ bias,
    float* __restrict__ out)
{
    __shared__ __bf16 Bs[128 * 128];     // 32 KB, swizzled

    const int t  = threadIdx.x;
    const int pt = blockIdx.x;           // 32
    const int ot = blockIdx.y;           // 4 (64 o each)
    const int b  = blockIdx.z;           // 4
    const int l = t & 63, lm = l & 15, q4 = l >> 4;
    const int w = __builtin_amdgcn_readfirstlane(t >> 6);
    const int p0 = pt * 128;
    const int o0w = ot * 64 + w * 16;
    const size_t per = (size_t)NBATCH * NTOK * HID;

    // staged combine: same (p_l, gc) gather as the old ASYNC16 loop, same
    // linear Bs destination (i*4+w)*1024 + lane*16.
#pragma unroll
    for (int i = 0; i < 8; ++i) {
        const int p_l = (i * 4 + w) * 4 + (l >> 4);
        const int gc  = (l & 15) ^ (p_l & 7);
        const int p   = p0 + p_l;
        const size_t base = ((size_t)(b * NTOK + p)) * HID + gc * 8;
        bf16x8 x0 = *(const bf16x8*)(Opart + base);
        bf16x8 x1 = *(const bf16x8*)(Opart + per + base);
        bf16x8 x2 = *(const bf16x8*)(Opart + 2 * per + base);
        bf16x8 x3 = *(const bf16x8*)(Opart + 3 * per + base);
        const int head = gc >> 2;        // 8 cols stay inside one head
        const size_t li = ((size_t)(b * HEADS + head)) * NTOK + p;
        const float inv = 1.f / (Lsum[li] + Lsum[li + 16 * NTOK] +
                                 Lsum[li + 32 * NTOK] + Lsum[li + 48 * NTOK]);
        bf16x8 o8;
#pragma unroll
        for (int u = 0; u < 8; ++u)
            o8[u] = (__bf16)((((float)x0[u] + (float)x1[u]) +
                              ((float)x2[u] + (float)x3[u])) * inv);
        *(bf16x8*)((char*)Bs + (i * 4 + w) * 1024 + l * 16) = o8;
    }

    bf16x8 af[4];
#pragma unroll
    for (int kt = 0; kt < 4; ++kt) {
        const float* wr = wo + (size_t)(o0w + lm) * HID + kt * 32 + q4 * 8;
        f32x4 w0 = *(const f32x4*)wr;
        f32x4 w1 = *(const f32x4*)(wr + 4);
#pragma unroll
        for (int u = 0; u < 4; ++u) {
            af[kt][u]     = (__bf16)w0[u];
            af[kt][u + 4] = (__bf16)w1[u];
        }
    }
    __syncthreads();

    f32x4 acc[8] = {};
#pragma unroll
    for (int kt = 0; kt < 4; ++kt) {
#pragma unroll
        for (int nf = 0; nf < 8; ++nf) {
            const int p = nf * 16 + lm;
            bf16x8 bf = *(const bf16x8*)(
                (const char*)Bs + p * 256 + (((kt * 4 + q4) ^ (lm & 7)) * 16));
            acc[nf] = MFMA(af[kt], bf, acc[nf], 0, 0, 0);
        }
    }

    const int og0 = o0w + q4 * 4;
#pragma unroll
    for (int nf = 0; nf < 8; ++nf) {
        const int p_g = p0 + nf * 16 + lm;
#pragma unroll
        for (int r = 0; r < 4; ++r)
            out[((size_t)(b * CDIM + og0 + r)) * NTOK + p_g] =
                acc[nf][r] + bias[og0 + r];
    }
}

// ---------------------------------------------------------------------------
extern "C" void kernel_launch(void* const* d_in, const int* in_sizes, int n_in,
                              void* d_out, int out_size, void* d_ws, size_t ws_size,
                              hipStream_t stream)
{
    const float* x     = (const float*)d_in[0];
    const float* w_qkv = (const float*)d_in[1];
    const float* w_out = (const float*)d_in[2];
    const float* b_out = (const float*)d_in[3];
    float* out = (float*)d_out;

    __bf16* Xt = (__bf16*)d_ws;                           // 8 MB
    __bf16* Q  = Xt + (size_t)NBATCH * NTOK * CDIM;       // 4 MB each
    __bf16* K  = Q  + (size_t)16 * NTOK * DHEAD;
    __bf16* Vt = K  + (size_t)16 * NTOK * DHEAD;
    __bf16* Opart = Vt + (size_t)16 * NTOK * DHEAD;       // 4 x 4 MB (bf16)
    float*  Lsum  = (float*)(Opart + (size_t)4 * NBATCH * NTOK * HID); // 4 x 256 KB

    cast_x  <<<dim3(64, 4, NBATCH), 256, 0, stream>>>(x, Xt);
    qkv_gemm<<<dim3(32, 6, NBATCH), 256, 0, stream>>>(w_qkv, Xt, Q, K, Vt);
    attn    <<<1024, 256, 0, stream>>>(Q, K, Vt, Opart, Lsum);
    out_gemm<<<dim3(32, 4, NBATCH), 256, 0, stream>>>(w_out, Opart, Lsum, b_out, out);
}